// Round 6
// baseline (736.529 us; speedup 1.0000x reference)
//
#include <hip/hip_runtime.h>
#include <hip/hip_bf16.h>

#define B_   8
#define NMAX 8192
#define C_   384
#define G_   512
#define K_   32
#define H_   6
#define DH_  64
#define CAP_ 64

typedef short bvec8 __attribute__((ext_vector_type(8)));
typedef short bvec4 __attribute__((ext_vector_type(4)));
typedef _Float16 hvec4 __attribute__((ext_vector_type(4)));
typedef float f32x4 __attribute__((ext_vector_type(4)));

__device__ __forceinline__ short f2bf(float f) {
    union { __hip_bfloat16 b; short s; } u;
    u.b = __float2bfloat16(f);
    return u.s;
}
__device__ __forceinline__ float bf2f(unsigned short u) {
    union { unsigned int i; float f; } w;
    w.i = ((unsigned int)u) << 16;
    return w.f;
}
__device__ __forceinline__ unsigned char f2fp8(float x) {
    return (unsigned char)(__builtin_amdgcn_cvt_pk_fp8_f32(x, x, 0, false) & 0xff);
}

// ---- LDS layout (bytes) ----
// [0, 24576)        xg [32 rows][768 B] bf16, XOR-swizzled (swzA).
// [24576 + h*4096)  per-head region, wave-private:
//                     phase 1: qf8 [32][64B] fp8 (swz8) at +0, kf8 at +2048
//                     phase 2 (after scores): attn_out stage [32 tok][128 B] bf16 (swzQ)
// [49152) mask 32 f32 ; [49280) idx 32 i32
#define HB_OFF    24576
#define MASK_OFF  49152
#define IDX_OFF   49280
#define LDS_BYTES 49408

__device__ __forceinline__ int swzA(int row, int colb) { return row * 768 + (colb ^ ((row & 7) << 4)); }
__device__ __forceinline__ int swzQ(int row, int colb) { return row * 128 + (colb ^ ((row & 7) << 4)); }
__device__ __forceinline__ int swz8(int row, int col)  { return row * 64  + (col  ^ ((row & 7) << 3)); }

// Pre-pack weights fragment-major so every attn-kernel weight fetch is one
// contiguous, coalesced 1KB wave-load:
//   wq_frag[(mat*6+h)*48 + kk*4 + nt][lane][8]  (tile = 512 bf16 = 1KB)
//   element (tile, lane, e) = W[mat*384 + h*64 + nt*16 + (lane&15)][kk*32 + (lane>>4)*8 + e]
__global__ void convw_kernel(const float* __restrict__ wqkv, const float* __restrict__ wproj,
                             short* __restrict__ wq_frag, short* __restrict__ wp_frag) {
    int i = blockIdx.x * 256 + threadIdx.x;     // chunk of 8 elems
    if (i < 55296) {                            // 864 tiles * 64 lanes (qkv)
        int lane = i & 63, t = i >> 6;
        int nt = t & 3, kk = (t >> 2) % 12, hh = (t >> 2) / 12;   // hh = mat*6+h
        int row  = hh * 64 + nt * 16 + (lane & 15);               // mat*384 + h*64 + ...
        int col0 = kk * 32 + (lane >> 4) * 8;
        const float* src = wqkv + (size_t)row * C_ + col0;
        bvec8 v;
        #pragma unroll
        for (int e = 0; e < 8; ++e) v[e] = f2bf(src[e]);
        *(bvec8*)(wq_frag + (size_t)i * 8) = v;
    } else if (i < 55296 + 18432) {             // 288 tiles * 64 lanes (proj)
        int j = i - 55296;
        int lane = j & 63, t = j >> 6;
        int nt = t & 3, kk = (t >> 2) % 12, h = (t >> 2) / 12;
        int row  = h * 64 + nt * 16 + (lane & 15);
        int col0 = kk * 32 + (lane >> 4) * 8;
        const float* src = wproj + (size_t)row * C_ + col0;
        bvec8 v;
        #pragma unroll
        for (int e = 0; e < 8; ++e) v[e] = f2bf(src[e]);
        *(bvec8*)(wp_frag + (size_t)j * 8) = v;
    }
}

// Build inverted index: per point, list of valid slot-ids (within batch).
__global__ void fill_kernel(const int* __restrict__ gidx, const float* __restrict__ gmask,
                            int* __restrict__ fillcnt, unsigned short* __restrict__ list) {
    int t = blockIdx.x * 256 + threadIdx.x;
    if (t >= B_ * G_ * K_) return;
    float m = gmask[t];
    if (m <= 0.f) return;
    int v = gidx[t];
    v = v < 0 ? 0 : v;
    int b = t >> 14;
    int bn = b * NMAX + v;
    int pos = atomicAdd(&fillcnt[bn], 1);
    if (pos < CAP_) list[(size_t)bn * CAP_ + pos] = (unsigned short)(t - (b << 14));
}

template<bool SLOT>
__global__ __launch_bounds__(384, 4) void attn_kernel(
    const float* __restrict__ feats, const int* __restrict__ gidx,
    const float* __restrict__ gmask, const short* __restrict__ wq_frag,
    const short* __restrict__ wp_frag, const float* __restrict__ bproj,
    float* __restrict__ acc_out, float* __restrict__ cnt,
    short* __restrict__ slotbuf) {
    extern __shared__ char sm[];
    float* mask_lds = (float*)(sm + MASK_OFF);
    int*   idx_lds  = (int*)(sm + IDX_OFF);

    const int tid  = threadIdx.x;
    const int lane = tid & 63;
    const int h    = tid >> 6;          // wave id = head id (0..5)
    const int bg   = blockIdx.x;        // group id within [0, B*G)
    const int b    = bg >> 9;
    const int l15  = lane & 15;
    const int l4   = lane >> 4;

    if (tid < 32) {
        int v = gidx[(size_t)bg * K_ + tid];
        v = v < 0 ? 0 : v;
        float m = gmask[(size_t)bg * K_ + tid];
        idx_lds[tid]  = v;
        mask_lds[tid] = m;
        if (!SLOT) {
            if (m > 0.f) atomicAdd(&cnt[b * NMAX + v], m);
        }
    }
    __syncthreads();

    // ---- gather: 32 rows x 384 fp32 -> bf16 LDS (swizzled); nontemporal (no reuse) ----
    #pragma unroll
    for (int i = 0; i < 8; ++i) {
        int p = i * 384 + tid;          // 3072 tasks, one f32x4 each
        int row = p / 96, seg = p % 96;
        f32x4 f = __builtin_nontemporal_load(
            (const f32x4*)(feats + ((size_t)(b * NMAX + idx_lds[row]) * C_ + seg * 4)));
        bvec4 v4 = { f2bf(f[0]), f2bf(f[1]), f2bf(f[2]), f2bf(f[3]) };
        *(bvec4*)(sm + swzA(row, seg * 8)) = v4;
    }
    __syncthreads();

    char* hb = sm + HB_OFF + h * 4096;   // wave-private head region
    char* qf = hb;
    char* kf = hb + 2048;

    // ---- merged q+k GEMM: two [32 x 64] outputs, one xg pass ----
    {
        f32x4 aq[2][4], ak[2][4];
        #pragma unroll
        for (int mt = 0; mt < 2; ++mt)
            #pragma unroll
            for (int nt = 0; nt < 4; ++nt) {
                aq[mt][nt] = (f32x4){0.f, 0.f, 0.f, 0.f};
                ak[mt][nt] = (f32x4){0.f, 0.f, 0.f, 0.f};
            }
        const short* wqb = wq_frag + (size_t)(h * 48) * 512;        // mat 0, head h
        const short* wkb = wq_frag + (size_t)((6 + h) * 48) * 512;  // mat 1, head h
        #pragma unroll
        for (int kk = 0; kk < 12; ++kk) {
            bvec8 a0 = *(const bvec8*)(sm + swzA(l15,      kk * 64 + l4 * 16));
            bvec8 a1 = *(const bvec8*)(sm + swzA(16 + l15, kk * 64 + l4 * 16));
            #pragma unroll
            for (int nt = 0; nt < 4; ++nt) {
                bvec8 fq = *(const bvec8*)(wqb + (size_t)((kk * 4 + nt) * 64 + lane) * 8);
                bvec8 fk = *(const bvec8*)(wkb + (size_t)((kk * 4 + nt) * 64 + lane) * 8);
                aq[0][nt] = __builtin_amdgcn_mfma_f32_16x16x32_bf16(a0, fq, aq[0][nt], 0, 0, 0);
                aq[1][nt] = __builtin_amdgcn_mfma_f32_16x16x32_bf16(a1, fq, aq[1][nt], 0, 0, 0);
                ak[0][nt] = __builtin_amdgcn_mfma_f32_16x16x32_bf16(a0, fk, ak[0][nt], 0, 0, 0);
                ak[1][nt] = __builtin_amdgcn_mfma_f32_16x16x32_bf16(a1, fk, ak[1][nt], 0, 0, 0);
            }
        }
        #pragma unroll
        for (int mt = 0; mt < 2; ++mt)
            #pragma unroll
            for (int nt = 0; nt < 4; ++nt)
                #pragma unroll
                for (int j = 0; j < 4; ++j) {
                    int r = mt * 16 + l4 * 4 + j, c = nt * 16 + l15;
                    *(unsigned char*)(qf + swz8(r, c)) = f2fp8(aq[mt][nt][j]);
                    *(unsigned char*)(kf + swz8(r, c)) = f2fp8(ak[mt][nt][j]);
                }
    }

    // ---- v GEMM: keep result in registers as f16 A-fragments ----
    hvec4 vfrag[2][4];
    {
        f32x4 av[2][4];
        #pragma unroll
        for (int mt = 0; mt < 2; ++mt)
            #pragma unroll
            for (int nt = 0; nt < 4; ++nt) av[mt][nt] = (f32x4){0.f, 0.f, 0.f, 0.f};
        const short* wvb = wq_frag + (size_t)((12 + h) * 48) * 512;  // mat 2, head h
        #pragma unroll
        for (int kk = 0; kk < 12; ++kk) {
            bvec8 a0 = *(const bvec8*)(sm + swzA(l15,      kk * 64 + l4 * 16));
            bvec8 a1 = *(const bvec8*)(sm + swzA(16 + l15, kk * 64 + l4 * 16));
            #pragma unroll
            for (int nt = 0; nt < 4; ++nt) {
                bvec8 fv = *(const bvec8*)(wvb + (size_t)((kk * 4 + nt) * 64 + lane) * 8);
                av[0][nt] = __builtin_amdgcn_mfma_f32_16x16x32_bf16(a0, fv, av[0][nt], 0, 0, 0);
                av[1][nt] = __builtin_amdgcn_mfma_f32_16x16x32_bf16(a1, fv, av[1][nt], 0, 0, 0);
            }
        }
        #pragma unroll
        for (int mt = 0; mt < 2; ++mt)
            #pragma unroll
            for (int nt = 0; nt < 4; ++nt)
                vfrag[mt][nt] = (hvec4){ (_Float16)av[mt][nt][0], (_Float16)av[mt][nt][1],
                                         (_Float16)av[mt][nt][2], (_Float16)av[mt][nt][3] };
    }

    // ---- scores^T = k @ q^T  (fp8, [32 keys x 32 qtok]) ----
    f32x4 sc[2][2];
    #pragma unroll
    for (int mt = 0; mt < 2; ++mt)
        #pragma unroll
        for (int nt = 0; nt < 2; ++nt) sc[mt][nt] = (f32x4){0.f, 0.f, 0.f, 0.f};
    #pragma unroll
    for (int kk = 0; kk < 2; ++kk) {
        long ka0 = *(const long*)(kf + swz8(l15,      kk * 32 + l4 * 8));
        long ka1 = *(const long*)(kf + swz8(16 + l15, kk * 32 + l4 * 8));
        long qa0 = *(const long*)(qf + swz8(l15,      kk * 32 + l4 * 8));
        long qa1 = *(const long*)(qf + swz8(16 + l15, kk * 32 + l4 * 8));
        sc[0][0] = __builtin_amdgcn_mfma_f32_16x16x32_fp8_fp8(ka0, qa0, sc[0][0], 0, 0, 0);
        sc[0][1] = __builtin_amdgcn_mfma_f32_16x16x32_fp8_fp8(ka0, qa1, sc[0][1], 0, 0, 0);
        sc[1][0] = __builtin_amdgcn_mfma_f32_16x16x32_fp8_fp8(ka1, qa0, sc[1][0], 0, 0, 0);
        sc[1][1] = __builtin_amdgcn_mfma_f32_16x16x32_fp8_fp8(ka1, qa1, sc[1][1], 0, 0, 0);
    }

    // ---- softmax over keys (keys in-register + across l4 groups) ----
    float bk[2][4];
    #pragma unroll
    for (int mt = 0; mt < 2; ++mt)
        #pragma unroll
        for (int j = 0; j < 4; ++j)
            bk[mt][j] = mask_lds[mt * 16 + l4 * 4 + j] > 0.f ? 0.f : -1e30f;

    hvec4 pfrag[2][2];   // [key chunk c][qtok tile qt]
    #pragma unroll
    for (int nt = 0; nt < 2; ++nt) {
        float s[2][4];
        float mx = -1e30f;
        #pragma unroll
        for (int mt = 0; mt < 2; ++mt)
            #pragma unroll
            for (int j = 0; j < 4; ++j) {
                s[mt][j] = sc[mt][nt][j] * 0.125f + bk[mt][j];
                mx = fmaxf(mx, s[mt][j]);
            }
        mx = fmaxf(mx, __shfl_xor(mx, 16));
        mx = fmaxf(mx, __shfl_xor(mx, 32));
        float sum = 0.f;
        #pragma unroll
        for (int mt = 0; mt < 2; ++mt)
            #pragma unroll
            for (int j = 0; j < 4; ++j) {
                s[mt][j] = __expf(s[mt][j] - mx);
                sum += s[mt][j];
            }
        sum += __shfl_xor(sum, 16);
        sum += __shfl_xor(sum, 32);
        float inv = 1.f / sum;
        #pragma unroll
        for (int mt = 0; mt < 2; ++mt)
            pfrag[mt][nt] = (hvec4){ (_Float16)(s[mt][0] * inv), (_Float16)(s[mt][1] * inv),
                                     (_Float16)(s[mt][2] * inv), (_Float16)(s[mt][3] * inv) };
    }

    // ---- PV: out^T[dh][qtok] via 16x16x16 f16 MFMA, all in registers ----
    f32x4 po[4][2];
    #pragma unroll
    for (int dt = 0; dt < 4; ++dt)
        #pragma unroll
        for (int qt = 0; qt < 2; ++qt) po[dt][qt] = (f32x4){0.f, 0.f, 0.f, 0.f};
    #pragma unroll
    for (int c = 0; c < 2; ++c)
        #pragma unroll
        for (int dt = 0; dt < 4; ++dt)
            #pragma unroll
            for (int qt = 0; qt < 2; ++qt)
                po[dt][qt] = __builtin_amdgcn_mfma_f32_16x16x16f16(vfrag[c][dt], pfrag[c][qt], po[dt][qt], 0, 0, 0);

    // stage attn_out into hb (q/k fp8 region dead now; wave-private, no barrier)
    #pragma unroll
    for (int dt = 0; dt < 4; ++dt)
        #pragma unroll
        for (int qt = 0; qt < 2; ++qt)
            #pragma unroll
            for (int j = 0; j < 4; ++j) {
                int tok = qt * 16 + l15;
                int ch  = dt * 16 + l4 * 4 + j;
                *(short*)(hb + swzQ(tok, ch * 2)) = f2bf(po[dt][qt][j]);
            }
    __syncthreads();   // all heads' attn_out staged before proj reads across heads

    // ---- proj: out[32 x 384] = attn_out @ w_proj^T ; wave h -> cols h*64.. ----
    f32x4 pr[2][4];
    #pragma unroll
    for (int mt = 0; mt < 2; ++mt)
        #pragma unroll
        for (int nt = 0; nt < 4; ++nt) pr[mt][nt] = (f32x4){0.f, 0.f, 0.f, 0.f};
    const short* wpb = wp_frag + (size_t)(h * 48) * 512;
    #pragma unroll
    for (int kk = 0; kk < 12; ++kk) {
        const char* st = sm + HB_OFF + (kk >> 1) * 4096;
        int colb = (kk & 1) * 64 + l4 * 16;
        bvec8 a0 = *(const bvec8*)(st + swzQ(l15,      colb));
        bvec8 a1 = *(const bvec8*)(st + swzQ(16 + l15, colb));
        #pragma unroll
        for (int nt = 0; nt < 4; ++nt) {
            bvec8 w = *(const bvec8*)(wpb + (size_t)((kk * 4 + nt) * 64 + lane) * 8);
            pr[0][nt] = __builtin_amdgcn_mfma_f32_16x16x32_bf16(a0, w, pr[0][nt], 0, 0, 0);
            pr[1][nt] = __builtin_amdgcn_mfma_f32_16x16x32_bf16(a1, w, pr[1][nt], 0, 0, 0);
        }
    }

    if constexpr (SLOT) {
        // xg region free now; stage proj+bias rows (bf16), then coalesced nontemporal store
        #pragma unroll
        for (int nt = 0; nt < 4; ++nt) {
            int c = h * DH_ + nt * 16 + l15;
            float bias = bproj[c];
            #pragma unroll
            for (int mt = 0; mt < 2; ++mt)
                #pragma unroll
                for (int j = 0; j < 4; ++j) {
                    int t = mt * 16 + l4 * 4 + j;
                    *(short*)(sm + swzA(t, c * 2)) = f2bf(pr[mt][nt][j] + bias);
                }
        }
        __syncthreads();
        #pragma unroll
        for (int i = 0; i < 4; ++i) {
            int chunk = i * 384 + tid;          // 1536 chunks of 16B
            int row = chunk / 48, off = chunk % 48;
            bvec8 v = *(const bvec8*)(sm + swzA(row, off * 16));
            __builtin_nontemporal_store(v,
                (bvec8*)(slotbuf + ((size_t)(bg * K_ + row)) * C_ + off * 8));
        }
    } else {
        #pragma unroll
        for (int nt = 0; nt < 4; ++nt) {
            int c = h * DH_ + nt * 16 + l15;
            float bias = bproj[c];
            #pragma unroll
            for (int mt = 0; mt < 2; ++mt)
                #pragma unroll
                for (int j = 0; j < 4; ++j) {
                    int t = mt * 16 + l4 * 4 + j;
                    float mk = mask_lds[t];
                    if (mk > 0.f) {
                        float val = pr[mt][nt][j] + bias;
                        atomicAdd(acc_out + (size_t)(b * NMAX + idx_lds[t]) * C_ + c, val);
                    }
                }
        }
    }
}

// Path A finalize: block per point, gather slot rows, average, add residual.
__global__ __launch_bounds__(192) void finalize2_kernel(
    const float* __restrict__ feats, const int* __restrict__ fillcnt,
    const unsigned short* __restrict__ list, const short* __restrict__ slotbuf,
    const float* __restrict__ gamma, float* __restrict__ out) {
    int bn = blockIdx.x;               // b * NMAX + n
    int b  = bn >> 13;
    int tid = threadIdx.x;             // 0..191, channel pair tid*2
    int c = fillcnt[bn];
    int cc = c < CAP_ ? c : CAP_;
    float ax = 0.f, ay = 0.f;
    const unsigned int* sb = (const unsigned int*)slotbuf;
    for (int e = 0; e < cc; ++e) {
        int sl = list[(size_t)bn * CAP_ + e];
        unsigned int w = __builtin_nontemporal_load(
            &sb[((size_t)(b << 14) + sl) * (C_ / 2) + tid]);
        ax += bf2f((unsigned short)(w & 0xffff));
        ay += bf2f((unsigned short)(w >> 16));
    }
    float inv = 1.f / (float)(c < 1 ? 1 : c);
    size_t o = (size_t)bn * C_ + tid * 2;
    float fx = feats[o], fy = feats[o + 1];
    float gx = gamma[tid * 2], gy = gamma[tid * 2 + 1];
    out[o]     = fx + ax * inv * gx;
    out[o + 1] = fy + ay * inv * gy;
}

// Path B finalize (fallback): out already holds atomic accumulator.
__global__ void finalize_kernel(const float* __restrict__ feats, const float* __restrict__ cnt,
                                const float* __restrict__ gamma, float* __restrict__ out) {
    size_t i4 = (size_t)blockIdx.x * 256 + threadIdx.x;
    const size_t total4 = (size_t)B_ * NMAX * C_ / 4;
    if (i4 >= total4) return;
    int n  = (int)(i4 / (C_ / 4));
    int c4 = (int)(i4 % (C_ / 4)) * 4;
    float cv = cnt[n];
    float inv = 1.f / (cv < 1.f ? 1.f : cv);
    f32x4 a = ((const f32x4*)out)[i4];
    f32x4 f = ((const f32x4*)feats)[i4];
    f32x4 g = *(const f32x4*)(gamma + c4);
    f32x4 r;
    r[0] = f[0] + a[0] * inv * g[0];
    r[1] = f[1] + a[1] * inv * g[1];
    r[2] = f[2] + a[2] * inv * g[2];
    r[3] = f[3] + a[3] * inv * g[3];
    ((f32x4*)out)[i4] = r;
}

extern "C" void kernel_launch(void* const* d_in, const int* in_sizes, int n_in,
                              void* d_out, int out_size, void* d_ws, size_t ws_size,
                              hipStream_t stream) {
    const float* feats = (const float*)d_in[0];
    const int*   gidx  = (const int*)d_in[1];
    const float* gmask = (const float*)d_in[2];
    const float* wqkv  = (const float*)d_in[3];
    const float* wproj = (const float*)d_in[4];
    const float* bproj = (const float*)d_in[5];
    const float* gamma = (const float*)d_in[6];
    float* out = (float*)d_out;

    char* ws = (char*)d_ws;
    short* wq_frag = (short*)ws;                            // 884736 B
    short* wp_frag = (short*)(ws + 884736);                 // 294912 B
    // Path A layout:
    int*            fillcnt = (int*)(ws + 1179648);         // 262144 B
    unsigned short* list    = (unsigned short*)(ws + 1441792);                 // 16 MiB
    short*          slotbuf = (short*)(ws + 1441792 + (size_t)B_*NMAX*CAP_*2); // ~100.7 MB
    const size_t neededA = 1441792 + (size_t)B_*NMAX*CAP_*2 + (size_t)B_*G_*K_*C_*2;
    // Path B layout (fallback):
    float* cnt = (float*)(ws + 1179648);

    convw_kernel<<<(55296 + 18432 + 255) / 256, 256, 0, stream>>>(wqkv, wproj, wq_frag, wp_frag);

    if (ws_size >= neededA) {
        (void)hipMemsetAsync(fillcnt, 0, (size_t)B_ * NMAX * sizeof(int), stream);
        fill_kernel<<<(B_ * G_ * K_ + 255) / 256, 256, 0, stream>>>(gidx, gmask, fillcnt, list);
        attn_kernel<true><<<B_ * G_, 384, LDS_BYTES, stream>>>(feats, gidx, gmask, wq_frag, wp_frag,
                                                               bproj, out, nullptr, slotbuf);
        finalize2_kernel<<<B_ * NMAX, 192, 0, stream>>>(feats, fillcnt, list, slotbuf, gamma, out);
    } else {
        (void)hipMemsetAsync(out, 0, (size_t)B_ * NMAX * C_ * sizeof(float), stream);
        (void)hipMemsetAsync(cnt, 0, (size_t)B_ * NMAX * sizeof(float), stream);
        attn_kernel<false><<<B_ * G_, 384, LDS_BYTES, stream>>>(feats, gidx, gmask, wq_frag, wp_frag,
                                                                bproj, out, cnt, nullptr);
        finalize_kernel<<<(B_ * NMAX * C_ / 4 + 255) / 256, 256, 0, stream>>>(feats, cnt, gamma, out);
    }
}